// Round 17
// baseline (567.832 us; speedup 1.0000x reference)
//
#include <hip/hip_runtime.h>
#include <hip/hip_bf16.h>

#define NN 20000
#define NE 300000
#define HIDN 128
#define NLAY 4
#define NNT32 ((NN + 31) / 32)     /* 625 */
#define EBLOCKS64 4688             /* (NE+63)/64 = 4688 = 8*586 exactly */
#define EB64_PER_XCD 586

typedef short short8 __attribute__((ext_vector_type(8)));
typedef float f32x4 __attribute__((ext_vector_type(4)));
typedef unsigned short us16;
typedef unsigned int u32;

__device__ __forceinline__ float lrelu(float x){ return x >= 0.f ? x : 0.2f * x; }
__device__ __forceinline__ float b2f(us16 u){ return __uint_as_float(((u32)u) << 16); }
__device__ __forceinline__ us16 f2b(float f){
    u32 u = __float_as_uint(f);
    u += 0x7FFFu + ((u >> 16) & 1u);
    return (us16)(u >> 16);
}
__device__ __forceinline__ float rawf(const void* p, size_t i, int dt){
    return dt ? b2f(((const us16*)p)[i]) : ((const float*)p)[i];
}
__device__ __forceinline__ void ld4f(const float* p, float* r){
    float4 v = *(const float4*)p; r[0]=v.x; r[1]=v.y; r[2]=v.z; r[3]=v.w;
}
// staging swizzle (u32 granularity): rows of 16 u32; XOR quads by (row>>1)&3
__device__ __forceinline__ int swzi(int i){
    return (i & ~15) | ((i & 15) ^ (((i >> 5) & 3) << 2));
}

__device__ __forceinline__ void ln_stats_128(float v, volatile float* red, float& mean, float& inv){
    float s = v, s2 = v * v;
#pragma unroll
    for (int m = 32; m >= 1; m >>= 1){ s += __shfl_xor(s, m, 64); s2 += __shfl_xor(s2, m, 64); }
    int w = threadIdx.x >> 6;
    if ((threadIdx.x & 63) == 0){ red[w*2] = s; red[w*2+1] = s2; }
    __syncthreads();
    float ts = red[0] + red[2], ts2 = red[1] + red[3];
    mean = ts * (1.f/128.f);
    float var = ts2 * (1.f/128.f) - mean * mean;
    inv = rsqrtf(var + 1e-5f);
    __syncthreads();
}

// ---------------- dtype detect + convert ----------------
__global__ void k_detect(const u32* __restrict__ ne_g, int* __restrict__ flag){
    flag[0] = (ne_g[0] == 0x3F803F80u) ? 1 : 0;
}

struct ConvEnt { const void* s; float* d; int n; int pad; };
struct ConvTab { ConvEnt c[28]; int cnt; int pad[3]; };

__global__ void k_convert_all(ConvTab tab, const int* __restrict__ flag){
    int ti = blockIdx.y;
    if (ti >= tab.cnt) return;
    const void* s = tab.c[ti].s;
    float* d = tab.c[ti].d;
    int n = tab.c[ti].n;
    int dt = flag[0];
    for (int i = blockIdx.x*blockDim.x + threadIdx.x; i < n; i += gridDim.x*blockDim.x)
        d[i] = rawf(s, i, dt);
}

// ---------------- bf16 weight prep ----------------
#define W1T (128*256)
#define W2S (4*128*32)
#define GWT (128*128)
#define PER_L (W1T + W2S + GWT)
#define PTOT2 (NLAY*PER_L)
__global__ void k_prepw(const void* __restrict__ ecw1r, const void* __restrict__ ecw2r,
                        const void* __restrict__ gatwr, const int* __restrict__ flag,
                        us16* __restrict__ w1t, us16* __restrict__ w2s, us16* __restrict__ gwt){
    int id = blockIdx.x*blockDim.x + threadIdx.x;
    if (id >= PTOT2) return;
    int dt = flag[0];
    int L = id / PER_L, r = id % PER_L;
    if (r < W1T){
        int n = r >> 8, k = r & 255;
        w1t[(size_t)L*W1T + r] = f2b(rawf(ecw1r, (size_t)L*32768 + (size_t)k*128 + n, dt));
    } else if (r < W1T + W2S){
        int rr = r - W1T;
        int kk = rr >> 12, rem = rr & 4095, n = rem >> 5, ks = rem & 31;
        int k = kk*32 + ks;
        w2s[(size_t)L*W2S + rr] = f2b(rawf(ecw2r, (size_t)L*16384 + (size_t)k*128 + n, dt));
    } else {
        int rr = r - W1T - W2S; int n = rr >> 7, k = rr & 127;
        gwt[(size_t)L*GWT + rr] = f2b(rawf(gatwr, (size_t)L*16384 + (size_t)k*128 + n, dt));
    }
}

// ---------------- CSR build ----------------
__global__ void k_hist(const int* __restrict__ dstI, int* __restrict__ cnt){
    int e = blockIdx.x*blockDim.x + threadIdx.x;
    if (e < NE) atomicAdd(&cnt[dstI[e]], 1);
}
__global__ void k_scan(const int* __restrict__ cnt, int* __restrict__ rowptr){
    __shared__ int ps[256];
    int t = threadIdx.x;
    int chunk = (NN + 255) / 256;
    int beg = t*chunk, end = beg + chunk; if (end > NN) end = NN;
    int s = 0;
    for (int i = beg; i < end; ++i) s += cnt[i];
    ps[t] = s; __syncthreads();
    int off = 0;
    for (int i = 0; i < t; ++i) off += ps[i];
    int run = off;
    for (int i = beg; i < end; ++i){ rowptr[i] = run; run += cnt[i]; }
    if (t == 255) rowptr[NN] = run;
}
__global__ void k_csrfill(const int* __restrict__ srcI, const int* __restrict__ dstI,
                          int* __restrict__ cur, int* __restrict__ csr_src,
                          int* __restrict__ csr_dst){
    int e = blockIdx.x*blockDim.x + threadIdx.x;
    if (e < NE){
        int d = dstI[e];
        int p = atomicAdd(&cur[d], 1);
        csr_src[p] = srcI[e];
        csr_dst[p] = d;
    }
}

// ---------------- node encoder ----------------
__global__ void k_nodeenc(const float* __restrict__ xf, const float* __restrict__ w,
                          const float* __restrict__ b, const float* __restrict__ g,
                          const float* __restrict__ beta, float* __restrict__ h,
                          us16* __restrict__ xb){
    __shared__ float red[4];
    int n = blockIdx.x, t = threadIdx.x;
    float acc = b[t];
#pragma unroll
    for (int k = 0; k < 4; ++k) acc = fmaf(xf[n*4+k], w[k*HIDN+t], acc);
    acc = lrelu(acc);
    float mean, inv; ln_stats_128(acc, red, mean, inv);
    float o = (acc-mean)*inv*g[t] + beta[t];
    h[(size_t)n*HIDN+t] = o;
    xb[(size_t)n*HIDN+t] = f2b(o);
}

// ---------------- per-node gate dots (layer 0 only) ----------------
__global__ void k_predot(const float* __restrict__ x, const float* __restrict__ wa,
                         const float* __restrict__ baP, float* __restrict__ gd,
                         float* __restrict__ gs){
    int wv = threadIdx.x >> 6, l = threadIdx.x & 63;
    int n = blockIdx.x*4 + wv;
    if (n >= NN) return;
    float2 xv = *(const float2*)(x + (size_t)n*HIDN + 2*l);
    float pd = xv.x*wa[2*l]     + xv.y*wa[2*l+1];
    float ps = xv.x*wa[128+2*l] + xv.y*wa[129+2*l];
#pragma unroll
    for (int mk = 32; mk >= 1; mk >>= 1){ pd += __shfl_xor(pd, mk, 64); ps += __shfl_xor(ps, mk, 64); }
    if (l == 0){ gd[n] = pd + baP[0]; gs[n] = ps; }
}

// ---------------- node GEMM: [y1|y2|wx] = x @ [W1a|W1b|gatw] + head dots ----------------
__global__ __launch_bounds__(256, 2) void k_nodemm(
    const us16* __restrict__ xb, const us16* __restrict__ w1t,
    const us16* __restrict__ gwt, const float* __restrict__ b1,
    const float* __restrict__ aws, const float* __restrict__ awd,
    us16* __restrict__ y1b, us16* __restrict__ y2b, us16* __restrict__ wxb,
    float* __restrict__ asrc, float* __restrict__ adst)
{
    __shared__ __align__(16) us16 sbuf[32*128];   // 8 KB
    int t = threadIdx.x;
    int wv = t >> 6, lane = t & 63, g = lane >> 4, lr = lane & 15;

    short8 fr[3][2][4];
#pragma unroll
    for (int m = 0; m < 3; ++m)
#pragma unroll
        for (int p = 0; p < 2; ++p){
            int crow = (wv + 4*p)*16 + lr;
#pragma unroll
            for (int kk = 0; kk < 4; ++kk){
                fr[m][p][kk] = (m < 2)
                    ? *(const short8*)(w1t + crow*256 + m*128 + kk*32 + g*8)
                    : *(const short8*)(gwt + crow*128 + kk*32 + g*8);
            }
        }
    float aw_s0 = aws[2*lane], aw_s1 = aws[2*lane+1];
    float aw_d0 = awd[2*lane], aw_d1 = awd[2*lane+1];
    float b1v[2][4];
#pragma unroll
    for (int p = 0; p < 2; ++p) ld4f(b1 + (wv + 4*p)*16 + g*4, b1v[p]);

    for (int tile = blockIdx.x; tile < NNT32; tile += gridDim.x){
        int n0 = tile * 32;
        f32x4 acc[3][2][2];
#pragma unroll
        for (int m = 0; m < 3; ++m)
#pragma unroll
            for (int p = 0; p < 2; ++p)
#pragma unroll
                for (int et = 0; et < 2; ++et) acc[m][p][et] = (f32x4)(0.f);

#pragma unroll
        for (int et = 0; et < 2; ++et){
            int nrow = n0 + et*16 + lr; if (nrow >= NN) nrow = NN - 1;
            short8 bF[4];
#pragma unroll
            for (int kk = 0; kk < 4; ++kk)
                bF[kk] = *(const short8*)(xb + (size_t)nrow*HIDN + kk*32 + g*8);
#pragma unroll
            for (int m = 0; m < 3; ++m)
#pragma unroll
                for (int p = 0; p < 2; ++p)
#pragma unroll
                    for (int kk = 0; kk < 4; ++kk)
                        acc[m][p][et] = __builtin_amdgcn_mfma_f32_16x16x32_bf16(fr[m][p][kk], bF[kk], acc[m][p][et], 0, 0, 0);
        }

#pragma unroll
        for (int m = 0; m < 3; ++m){
#pragma unroll
            for (int p = 0; p < 2; ++p)
#pragma unroll
                for (int et = 0; et < 2; ++et){
                    int row = et*16 + lr;
                    int swz = (row & 7) << 3;
                    int c0 = (wv + 4*p)*16 + g*4;
#pragma unroll
                    for (int r = 0; r < 4; ++r){
                        float v = acc[m][p][et][r] + ((m == 0) ? b1v[p][r] : 0.f);
                        sbuf[row*128 + ((c0 + r) ^ swz)] = f2b(v);
                    }
                }
            __syncthreads();
            us16* dst = (m == 0) ? y1b : (m == 1) ? y2b : wxb;
            {
                int row = t >> 3, q = t & 7;
                int n = n0 + row;
                if (n < NN){
                    int swz = (row & 7) << 3;
#pragma unroll
                    for (int j = 0; j < 2; ++j){
                        int col = q*16 + j*8;
                        *(short8*)(dst + (size_t)n*HIDN + col) = *(const short8*)(sbuf + row*128 + (col ^ swz));
                    }
                }
            }
            if (m == 2){
#pragma unroll
                for (int i = 0; i < 8; ++i){
                    int rw = wv*8 + i;
                    int n2 = n0 + rw;
                    int ci = (2*lane) ^ ((rw & 7) << 3);
                    u32 v = *(const u32*)(sbuf + rw*128 + ci);
                    float x0 = b2f((us16)(v & 0xFFFFu)), x1 = b2f((us16)(v >> 16));
                    float ps = x0*aw_s0 + x1*aw_s1;
                    float pd = x0*aw_d0 + x1*aw_d1;
#pragma unroll
                    for (int mk = 8; mk >= 1; mk >>= 1){ ps += __shfl_xor(ps, mk, 64); pd += __shfl_xor(pd, mk, 64); }
                    if ((lane & 15) == 0 && n2 < NN){
                        int h = lane >> 4;
                        asrc[(size_t)n2*4 + h] = ps;
                        adst[(size_t)n2*4 + h] = pd;
                    }
                }
            }
            __syncthreads();
        }
    }
}

// ---------------- edge kernel: in-register A-frags, 64 edges/block, wave-local out ----------------
__global__ __launch_bounds__(256, 4) void k_edgeconv2(
    const us16* __restrict__ y1b, const us16* __restrict__ y2b,
    const int* __restrict__ csr_src, const int* __restrict__ csr_dst,
    const us16* __restrict__ w2s, const float* __restrict__ lngE,
    const float* __restrict__ lnbE, const float* __restrict__ b2,
    const float* __restrict__ gd, const float* __restrict__ gs,
    us16* __restrict__ msg)
{
    __shared__ __align__(16) u32 bsl[2][2048];   // 16 KB dbuf W2 slices
    __shared__ __align__(16) us16 outS[4*16*128]; // 16 KB, 4 KB per wave
    int t = threadIdx.x;
    int wv = t >> 6, lane = t & 63, g = lane >> 4, lr = lane & 15;
    int bid = (int)blockIdx.x;
    int sb = (bid & 7) * EB64_PER_XCD + (bid >> 3);
    int e0 = sb * 64;

    const u32* w2u = (const u32*)w2s;
    u32 rS[8];
#pragma unroll
    for (int q = 0; q < 8; ++q) rS[q] = w2u[t + 256*q];   // slice 0 issued early

    // ---- phase A (register-resident): gather 32 channels of edge lr ----
    int e = e0 + wv*16 + lr;
    int ec = (e < NE) ? e : NE - 1;
    int d = csr_dst[ec], s = csr_src[ec];
    float gate = 1.f / (1.f + __expf(-(gd[d] + gs[s])));

    float vv[32];
    {
        short8 ra[4], rb[4];
#pragma unroll
        for (int kk = 0; kk < 4; ++kk){
            ra[kk] = *(const short8*)(y1b + (size_t)d*HIDN + kk*32 + g*8);
            rb[kk] = *(const short8*)(y2b + (size_t)s*HIDN + kk*32 + g*8);
        }
        float s1 = 0.f, s2 = 0.f;
#pragma unroll
        for (int kk = 0; kk < 4; ++kk)
#pragma unroll
            for (int j = 0; j < 8; ++j){
                float v = lrelu(b2f((us16)ra[kk][j]) + b2f((us16)rb[kk][j]));
                vv[kk*8+j] = v; s1 += v; s2 += v*v;
            }
        s1 += __shfl_xor(s1, 16, 64); s2 += __shfl_xor(s2, 16, 64);
        s1 += __shfl_xor(s1, 32, 64); s2 += __shfl_xor(s2, 32, 64);
        float mean = s1 * (1.f/128.f);
        float var  = s2 * (1.f/128.f) - mean*mean;
        float inv  = rsqrtf(var + 1e-5f);
#pragma unroll
        for (int kk = 0; kk < 4; ++kk){
            float lg[4], lg2[4], lb[4], lb2[4];
            int c0 = kk*32 + g*8;
            ld4f(lngE + c0, lg);  ld4f(lngE + c0 + 4, lg2);
            ld4f(lnbE + c0, lb);  ld4f(lnbE + c0 + 4, lb2);
#pragma unroll
            for (int j = 0; j < 4; ++j){
                vv[kk*8+j]   = (vv[kk*8+j]   - mean)*inv*lg[j]  + lb[j];
                vv[kk*8+4+j] = (vv[kk*8+4+j] - mean)*inv*lg2[j] + lb2[j];
            }
        }
    }
    short8 aF[4];
#pragma unroll
    for (int kk = 0; kk < 4; ++kk)
#pragma unroll
        for (int j = 0; j < 8; ++j)
            aF[kk][j] = (short)f2b(vv[kk*8+j]);

    // stage W2 slice 0, prefetch slice 1
#pragma unroll
    for (int q = 0; q < 8; ++q) bsl[0][swzi(t + 256*q)] = rS[q];
#pragma unroll
    for (int q = 0; q < 8; ++q) rS[q] = w2u[2048 + t + 256*q];
    __syncthreads();

    // ---- GEMM2: [16 edges x 128] @ [128 x 128] per wave, 4 K-phases ----
    f32x4 acc[8];
#pragma unroll
    for (int nt = 0; nt < 8; ++nt) acc[nt] = (f32x4)(0.f);
#pragma unroll
    for (int kk = 0; kk < 4; ++kk){
        const us16* bp = (const us16*)bsl[kk & 1];
#pragma unroll
        for (int nt = 0; nt < 8; ++nt){
            int row = nt*16 + lr;
            short8 bF = *(const short8*)(bp + row*32 + (g*8 ^ (((row>>1)&3)<<3)));
            acc[nt] = __builtin_amdgcn_mfma_f32_16x16x32_bf16(aF[kk], bF, acc[nt], 0, 0, 0);
        }
        if (kk < 3){
#pragma unroll
            for (int q = 0; q < 8; ++q) bsl[(kk+1)&1][swzi(t + 256*q)] = rS[q];
            if (kk < 2){
#pragma unroll
                for (int q = 0; q < 8; ++q) rS[q] = w2u[(kk+2)*2048 + t + 256*q];
            }
            __syncthreads();
        }
    }

    // ---- epilogue: bias + lrelu + gate -> wave-local outS ----
    float b2v[8];
#pragma unroll
    for (int nt = 0; nt < 8; ++nt) b2v[nt] = b2[nt*16 + lr];
    us16* os = outS + wv*2048;
#pragma unroll
    for (int r = 0; r < 4; ++r){
        int i = g*4 + r;
        float gi = __shfl(gate, i, 64);
        int swz = (i & 7) << 3;
#pragma unroll
        for (int nt = 0; nt < 8; ++nt){
            float v = lrelu(acc[nt][r] + b2v[nt]) * gi;
            os[i*128 + ((nt*16 + lr) ^ swz)] = f2b(v);
        }
    }
    {
        int row = lane >> 2, q = lane & 3;
        int ew = e0 + wv*16 + row;
        if (ew < NE){
            int swz = (row & 7) << 3;
#pragma unroll
            for (int j = 0; j < 4; ++j){
                int col = q*32 + j*8;
                *(short8*)(msg + (size_t)ew*HIDN + col) = *(const short8*)(os + row*128 + (col ^ swz));
            }
        }
    }
}

// ---------------- fused node update (2-deep pipeline + fused next-layer gate dots) ----------------
__global__ __launch_bounds__(256, 8) void k_node_update(
    const int* __restrict__ rowptr, const int* __restrict__ csr_src,
    const us16* __restrict__ msg, const us16* __restrict__ wxb,
    const float* __restrict__ asrc, const float* __restrict__ adst,
    const float* __restrict__ xc, const float* __restrict__ gbias,
    const float* __restrict__ lng, const float* __restrict__ lnb,
    float* __restrict__ xout, us16* __restrict__ xbout, int maxmode,
    const float* __restrict__ wa_next, const float* __restrict__ ba_next,
    float* __restrict__ gd, float* __restrict__ gs, int has_next)
{
    int wv = threadIdx.x >> 6, l = threadIdx.x & 63;
    int n = blockIdx.x*4 + wv;
    if (n >= NN) return;
    int c0 = 2*l, c1 = 2*l + 1;
    int h = l >> 4;

    int b = rowptr[n], en = rowptr[n+1];
    int deg = en - b;

    float adst_h = adst[(size_t)n*4 + h];
    float pself = __expf(fminf(lrelu(asrc[(size_t)n*4 + h] + adst_h), 80.f));
    u32 wq = *(const u32*)(wxb + (size_t)n*HIDN + c0);
    float att0 = pself * b2f((us16)(wq & 0xFFFFu));
    float att1 = pself * b2f((us16)(wq >> 16));
    float den = pself;

    float agg0, agg1;
    if (maxmode){ agg0 = agg1 = -3.0e38f; } else { agg0 = agg1 = 0.f; }

    // 2-deep pipeline: value loads for edge i+1 issued while processing edge i
    float asrA = 0.f; u32 wqA = 0, mqA = 0;
    if (deg > 0){
        int s0 = csr_src[b];
        asrA = asrc[(size_t)s0*4 + h];
        wqA  = *(const u32*)(wxb + (size_t)s0*HIDN + c0);
        mqA  = *(const u32*)(msg + (size_t)b*HIDN + c0);
    }
    for (int i = b; i < en; ++i){
        float asr = asrA; u32 wq2 = wqA; u32 mq = mqA;
        if (i + 1 < en){
            int sN = csr_src[i + 1];
            asrA = asrc[(size_t)sN*4 + h];
            wqA  = *(const u32*)(wxb + (size_t)sN*HIDN + c0);
            mqA  = *(const u32*)(msg + (size_t)(i + 1)*HIDN + c0);
        }
        float m0 = b2f((us16)(mq & 0xFFFFu)), m1 = b2f((us16)(mq >> 16));
        if (maxmode){ agg0 = fmaxf(agg0, m0); agg1 = fmaxf(agg1, m1); }
        else        { agg0 += m0; agg1 += m1; }
        float p = __expf(fminf(lrelu(asr + adst_h), 80.f));
        att0 = fmaf(p, b2f((us16)(wq2 & 0xFFFFu)), att0);
        att1 = fmaf(p, b2f((us16)(wq2 >> 16)), att1);
        den += p;
    }
    float rden = 1.f / den;
    att0 *= rden; att1 *= rden;
    if (maxmode){ if (deg == 0){ agg0 = 0.f; agg1 = 0.f; } }
    else { float rd = 1.f / fmaxf((float)deg, 1.f); agg0 *= rd; agg1 *= rd; }

    float2 xcv = *(const float2*)(xc + (size_t)n*HIDN + c0);
    float s0v = xcv.x + agg0 + att0 + gbias[c0];
    float s1v = xcv.y + agg1 + att1 + gbias[c1];

    float ss = s0v + s1v, ss2 = s0v*s0v + s1v*s1v;
#pragma unroll
    for (int mk = 32; mk >= 1; mk >>= 1){ ss += __shfl_xor(ss, mk, 64); ss2 += __shfl_xor(ss2, mk, 64); }
    float mean = ss * (1.f/128.f);
    float var  = ss2 * (1.f/128.f) - mean*mean;
    float inv  = rsqrtf(var + 1e-5f);
    float o0 = lrelu((s0v-mean)*inv*lng[c0] + lnb[c0]);
    float o1 = lrelu((s1v-mean)*inv*lng[c1] + lnb[c1]);
    *(float2*)(xout + (size_t)n*HIDN + c0) = make_float2(o0, o1);
    u32 pk = (u32)f2b(o0) | ((u32)f2b(o1) << 16);
    *(u32*)(xbout + (size_t)n*HIDN + c0) = pk;

    // fused next-layer gate dots: gd = wa_d . x_next + ba ; gs = wa_s . x_next
    if (has_next){
        float pd = o0*wa_next[c0]       + o1*wa_next[c1];
        float ps = o0*wa_next[128 + c0] + o1*wa_next[128 + c1];
#pragma unroll
        for (int mk = 32; mk >= 1; mk >>= 1){ pd += __shfl_xor(pd, mk, 64); ps += __shfl_xor(ps, mk, 64); }
        if (l == 0){ gd[n] = pd + ba_next[0]; gs[n] = ps; }
    }
}

// ---------------- dueling heads ----------------
__global__ void k_heads(const float* __restrict__ xc,
                        const float* __restrict__ aw1, const float* __restrict__ ab1,
                        const float* __restrict__ ag,  const float* __restrict__ abeta,
                        const float* __restrict__ aw2, const float* __restrict__ ab2,
                        const float* __restrict__ vw1, const float* __restrict__ vb1,
                        const float* __restrict__ vg,  const float* __restrict__ vbeta,
                        const float* __restrict__ vw2, const float* __restrict__ vb2,
                        void* __restrict__ dout, const int* __restrict__ flag){
    __shared__ float red[4];
    __shared__ float ts[128], u1[128], aout[10];
    int t = threadIdx.x;
    ts[t] = xc[t];
    __syncthreads();
    float acc = ab1[t];
    for (int k = 0; k < 128; ++k) acc = fmaf(ts[k], aw1[k*HIDN+t], acc);
    acc = lrelu(acc);
    float mean, inv; ln_stats_128(acc, red, mean, inv);
    u1[t] = (acc-mean)*inv*ag[t] + abeta[t];
    __syncthreads();
    if (t < 10){
        float a = ab2[t];
        for (int k = 0; k < 128; ++k) a = fmaf(u1[k], aw2[k*10+t], a);
        aout[t] = a;
    }
    __syncthreads();
    float accv = vb1[t];
    for (int k = 0; k < 128; ++k) accv = fmaf(ts[k], vw1[k*HIDN+t], accv);
    accv = lrelu(accv);
    float meanv, invv; ln_stats_128(accv, red, meanv, invv);
    float v1 = (accv-meanv)*invv*vg[t] + vbeta[t];
    float pv = v1 * vw2[t];
#pragma unroll
    for (int m = 32; m >= 1; m >>= 1) pv += __shfl_xor(pv, m, 64);
    if ((t & 63) == 0) red[t >> 6] = pv;
    __syncthreads();
    if (t == 0){
        float v = red[0] + red[1] + vb2[0];
        float am = 0.f;
        for (int j = 0; j < 10; ++j) am += aout[j];
        am *= 0.1f;
        int dt = flag[0];
        for (int j = 0; j < 11; ++j){
            float val = (j < 10) ? (v + aout[j] - am) : v;
            if (dt) ((__hip_bfloat16*)dout)[j] = __float2bfloat16(val);
            else    ((float*)dout)[j] = val;
        }
    }
}

extern "C" void kernel_launch(void* const* d_in, const int* in_sizes, int n_in,
                              void* d_out, int out_size, void* d_ws, size_t ws_size,
                              hipStream_t stream)
{
    float* base = (float*)d_ws;
    size_t off = 0;
    auto A = [&](size_t n)->float*{ float* p = base + off; off += (n + 63) & ~(size_t)63; return p; };

    int*   flag   = (int*)A(64);
    float* xf     = A((size_t)NN*4);
    float* new_w  = A(4*HIDN); float* neb = A(HIDN); float* neg_ = A(HIDN); float* nebeta = A(HIDN);
    float* ecb1   = A(NLAY*HIDN);
    float* eclng  = A(NLAY*HIDN); float* eclnb = A(NLAY*HIDN);
    float* ecb2   = A(NLAY*HIDN);
    float* ecwa   = A(NLAY*256);  float* ecba = A(NLAY);
    float* gasrc  = A(NLAY*HIDN); float* gadst = A(NLAY*HIDN); float* gbias = A(NLAY*HIDN);
    float* lng    = A(NLAY*HIDN); float* lnb = A(NLAY*HIDN);
    float* aw1    = A(HIDN*HIDN); float* ab1 = A(HIDN); float* ag = A(HIDN); float* abeta = A(HIDN);
    float* aw2    = A(HIDN*10);   float* ab2 = A(10);
    float* vw1    = A(HIDN*HIDN); float* vb1 = A(HIDN); float* vg = A(HIDN); float* vbeta = A(HIDN);
    float* vw2    = A(HIDN);      float* vb2 = A(1);
    // bf16 weights
    us16* w1t = (us16*)A((size_t)NLAY*W1T/2);
    us16* w2s = (us16*)A((size_t)NLAY*W2S/2);
    us16* gwt = (us16*)A((size_t)NLAY*GWT/2);
    // node buffers
    us16* xb   = (us16*)A((size_t)NN*HIDN/2);
    us16* wxb  = (us16*)A((size_t)NN*HIDN/2);
    us16* y1b  = (us16*)A((size_t)NN*HIDN/2);
    us16* y2b  = (us16*)A((size_t)NN*HIDN/2);
    float* xcA = A((size_t)NN*HIDN);
    float* xcB = A((size_t)NN*HIDN);
    float* gd  = A(NN); float* gs = A(NN);
    // CSR + small
    int* cnt     = (int*)A(NN);
    int* rowptr  = (int*)A(NN+1);
    int* cur     = (int*)A(NN);
    int* csr_src = (int*)A(NE);
    int* csr_dst = (int*)A(NE);
    float* asrc = A(NN*4); float* adst = A(NN*4);
    // messages (CSR-ordered)
    us16* msg = (us16*)A((size_t)NE*HIDN/2);

    const int* ei   = (const int*)d_in[1];
    const int* srcI = ei;
    const int* dstI = ei + NE;

    k_detect<<<1, 1, 0, stream>>>((const u32*)d_in[5], flag);

    ConvTab tab; int cc = 0;
    auto add = [&](int idx, float* dst, int n){ tab.c[cc].s = d_in[idx]; tab.c[cc].d = dst; tab.c[cc].n = n; tab.c[cc].pad = 0; cc++; };
    add(0,  xf,    NN*4);
    add(3,  new_w, 4*HIDN); add(4, neb, HIDN); add(5, neg_, HIDN); add(6, nebeta, HIDN);
    add(12, ecb1, NLAY*HIDN);
    add(13, eclng, NLAY*HIDN);     add(14, eclnb, NLAY*HIDN);
    add(16, ecb2, NLAY*HIDN);
    add(17, ecwa, NLAY*256);       add(18, ecba, NLAY);
    add(20, gasrc, NLAY*HIDN); add(21, gadst, NLAY*HIDN); add(22, gbias, NLAY*HIDN);
    add(23, lng,   NLAY*HIDN); add(24, lnb, NLAY*HIDN);
    add(25, aw1, HIDN*HIDN); add(26, ab1, HIDN); add(27, ag, HIDN); add(28, abeta, HIDN);
    add(29, aw2, HIDN*10);   add(30, ab2, 10);
    add(31, vw1, HIDN*HIDN); add(32, vb1, HIDN); add(33, vg, HIDN); add(34, vbeta, HIDN);
    add(35, vw2, HIDN);      add(36, vb2, 1);
    tab.cnt = cc;
    dim3 cgrid(64, cc);
    k_convert_all<<<cgrid, 256, 0, stream>>>(tab, flag);

    k_prepw<<<(PTOT2+255)/256, 256, 0, stream>>>(d_in[11], d_in[15], d_in[19],
                                                 flag, w1t, w2s, gwt);

    hipMemsetAsync(cnt, 0, NN*sizeof(int), stream);
    k_hist<<<(NE+255)/256, 256, 0, stream>>>(dstI, cnt);
    k_scan<<<1, 256, 0, stream>>>(cnt, rowptr);
    hipMemcpyAsync(cur, rowptr, NN*sizeof(int), hipMemcpyDeviceToDevice, stream);
    k_csrfill<<<(NE+255)/256, 256, 0, stream>>>(srcI, dstI, cur, csr_src, csr_dst);

    k_nodeenc<<<NN, 128, 0, stream>>>(xf, new_w, neb, neg_, nebeta, xcA, xb);

    float* curx = xcA; float* nxt = xcB;
    int nblocks4 = (NN + 3) / 4;
    // gate dots for layer 0
    k_predot<<<nblocks4, 256, 0, stream>>>(xcA, ecwa, ecba, gd, gs);

    for (int i = 0; i < NLAY; ++i){
        int maxmode = (i % 2 == 0);
        int has_next = (i + 1 < NLAY);

        k_nodemm<<<NNT32, 256, 0, stream>>>(xb, w1t + (size_t)i*W1T,
            gwt + (size_t)i*GWT, ecb1 + i*HIDN,
            gasrc + i*HIDN, gadst + i*HIDN,
            y1b, y2b, wxb, asrc, adst);

        k_edgeconv2<<<EBLOCKS64, 256, 0, stream>>>(y1b, y2b, csr_src, csr_dst,
            w2s + (size_t)i*W2S, eclng + i*HIDN, eclnb + i*HIDN,
            ecb2 + i*HIDN, gd, gs, msg);

        k_node_update<<<nblocks4, 256, 0, stream>>>(rowptr, csr_src, msg, wxb,
            asrc, adst, curx, gbias + i*HIDN, lng + i*HIDN, lnb + i*HIDN,
            nxt, xb, maxmode,
            ecwa + (i+1)*256, ecba + (i+1), gd, gs, has_next);

        float* tswap = curx; curx = nxt; nxt = tswap;
    }

    k_heads<<<1, 128, 0, stream>>>(curx, aw1, ab1, ag, abeta, aw2, ab2,
                                   vw1, vb1, vg, vbeta, vw2, vb2, d_out, flag);
}

// Round 18
// 540.255 us; speedup vs baseline: 1.0510x; 1.0510x over previous
//
#include <hip/hip_runtime.h>
#include <hip/hip_bf16.h>

#define NN 20000
#define NE 300000
#define HIDN 128
#define NLAY 4
#define NNT32 ((NN + 31) / 32)     /* 625 */
#define EBLOCKS64 4688             /* (NE+63)/64 = 4688 = 8*586 exactly */
#define EB64_PER_XCD 586

typedef short short8 __attribute__((ext_vector_type(8)));
typedef float f32x4 __attribute__((ext_vector_type(4)));
typedef unsigned short us16;
typedef unsigned int u32;

__device__ __forceinline__ float lrelu(float x){ return x >= 0.f ? x : 0.2f * x; }
__device__ __forceinline__ float b2f(us16 u){ return __uint_as_float(((u32)u) << 16); }
__device__ __forceinline__ us16 f2b(float f){
    u32 u = __float_as_uint(f);
    u += 0x7FFFu + ((u >> 16) & 1u);
    return (us16)(u >> 16);
}
__device__ __forceinline__ float rawf(const void* p, size_t i, int dt){
    return dt ? b2f(((const us16*)p)[i]) : ((const float*)p)[i];
}
__device__ __forceinline__ void ld4f(const float* p, float* r){
    float4 v = *(const float4*)p; r[0]=v.x; r[1]=v.y; r[2]=v.z; r[3]=v.w;
}
// staging swizzle (u32 granularity): rows of 16 u32; XOR quads by (row>>1)&3
__device__ __forceinline__ int swzi(int i){
    return (i & ~15) | ((i & 15) ^ (((i >> 5) & 3) << 2));
}

__device__ __forceinline__ void ln_stats_128(float v, volatile float* red, float& mean, float& inv){
    float s = v, s2 = v * v;
#pragma unroll
    for (int m = 32; m >= 1; m >>= 1){ s += __shfl_xor(s, m, 64); s2 += __shfl_xor(s2, m, 64); }
    int w = threadIdx.x >> 6;
    if ((threadIdx.x & 63) == 0){ red[w*2] = s; red[w*2+1] = s2; }
    __syncthreads();
    float ts = red[0] + red[2], ts2 = red[1] + red[3];
    mean = ts * (1.f/128.f);
    float var = ts2 * (1.f/128.f) - mean * mean;
    inv = rsqrtf(var + 1e-5f);
    __syncthreads();
}

// ---------------- dtype detect + convert ----------------
__global__ void k_detect(const u32* __restrict__ ne_g, int* __restrict__ flag){
    flag[0] = (ne_g[0] == 0x3F803F80u) ? 1 : 0;
}

struct ConvEnt { const void* s; float* d; int n; int pad; };
struct ConvTab { ConvEnt c[28]; int cnt; int pad[3]; };

__global__ void k_convert_all(ConvTab tab, const int* __restrict__ flag){
    int ti = blockIdx.y;
    if (ti >= tab.cnt) return;
    const void* s = tab.c[ti].s;
    float* d = tab.c[ti].d;
    int n = tab.c[ti].n;
    int dt = flag[0];
    for (int i = blockIdx.x*blockDim.x + threadIdx.x; i < n; i += gridDim.x*blockDim.x)
        d[i] = rawf(s, i, dt);
}

// ---------------- bf16 weight prep ----------------
#define W1T (128*256)
#define W2S (4*128*32)
#define GWT (128*128)
#define PER_L (W1T + W2S + GWT)
#define PTOT2 (NLAY*PER_L)
__global__ void k_prepw(const void* __restrict__ ecw1r, const void* __restrict__ ecw2r,
                        const void* __restrict__ gatwr, const int* __restrict__ flag,
                        us16* __restrict__ w1t, us16* __restrict__ w2s, us16* __restrict__ gwt){
    int id = blockIdx.x*blockDim.x + threadIdx.x;
    if (id >= PTOT2) return;
    int dt = flag[0];
    int L = id / PER_L, r = id % PER_L;
    if (r < W1T){
        int n = r >> 8, k = r & 255;
        w1t[(size_t)L*W1T + r] = f2b(rawf(ecw1r, (size_t)L*32768 + (size_t)k*128 + n, dt));
    } else if (r < W1T + W2S){
        int rr = r - W1T;
        int kk = rr >> 12, rem = rr & 4095, n = rem >> 5, ks = rem & 31;
        int k = kk*32 + ks;
        w2s[(size_t)L*W2S + rr] = f2b(rawf(ecw2r, (size_t)L*16384 + (size_t)k*128 + n, dt));
    } else {
        int rr = r - W1T - W2S; int n = rr >> 7, k = rr & 127;
        gwt[(size_t)L*GWT + rr] = f2b(rawf(gatwr, (size_t)L*16384 + (size_t)k*128 + n, dt));
    }
}

// ---------------- CSR build ----------------
__global__ void k_hist(const int* __restrict__ dstI, int* __restrict__ cnt){
    int e = blockIdx.x*blockDim.x + threadIdx.x;
    if (e < NE) atomicAdd(&cnt[dstI[e]], 1);
}
__global__ void k_scan(const int* __restrict__ cnt, int* __restrict__ rowptr){
    __shared__ int ps[256];
    int t = threadIdx.x;
    int chunk = (NN + 255) / 256;
    int beg = t*chunk, end = beg + chunk; if (end > NN) end = NN;
    int s = 0;
    for (int i = beg; i < end; ++i) s += cnt[i];
    ps[t] = s; __syncthreads();
    int off = 0;
    for (int i = 0; i < t; ++i) off += ps[i];
    int run = off;
    for (int i = beg; i < end; ++i){ rowptr[i] = run; run += cnt[i]; }
    if (t == 255) rowptr[NN] = run;
}
__global__ void k_csrfill(const int* __restrict__ srcI, const int* __restrict__ dstI,
                          int* __restrict__ cur, int* __restrict__ csr_src,
                          int* __restrict__ csr_dst){
    int e = blockIdx.x*blockDim.x + threadIdx.x;
    if (e < NE){
        int d = dstI[e];
        int p = atomicAdd(&cur[d], 1);
        csr_src[p] = srcI[e];
        csr_dst[p] = d;
    }
}

// ---------------- node encoder ----------------
__global__ void k_nodeenc(const float* __restrict__ xf, const float* __restrict__ w,
                          const float* __restrict__ b, const float* __restrict__ g,
                          const float* __restrict__ beta, float* __restrict__ h,
                          us16* __restrict__ xb){
    __shared__ float red[4];
    int n = blockIdx.x, t = threadIdx.x;
    float acc = b[t];
#pragma unroll
    for (int k = 0; k < 4; ++k) acc = fmaf(xf[n*4+k], w[k*HIDN+t], acc);
    acc = lrelu(acc);
    float mean, inv; ln_stats_128(acc, red, mean, inv);
    float o = (acc-mean)*inv*g[t] + beta[t];
    h[(size_t)n*HIDN+t] = o;
    xb[(size_t)n*HIDN+t] = f2b(o);
}

// ---------------- per-node gate dots ----------------
__global__ void k_predot(const float* __restrict__ x, const float* __restrict__ wa,
                         const float* __restrict__ baP, float* __restrict__ gd,
                         float* __restrict__ gs){
    int wv = threadIdx.x >> 6, l = threadIdx.x & 63;
    int n = blockIdx.x*4 + wv;
    if (n >= NN) return;
    float2 xv = *(const float2*)(x + (size_t)n*HIDN + 2*l);
    float pd = xv.x*wa[2*l]     + xv.y*wa[2*l+1];
    float ps = xv.x*wa[128+2*l] + xv.y*wa[129+2*l];
#pragma unroll
    for (int mk = 32; mk >= 1; mk >>= 1){ pd += __shfl_xor(pd, mk, 64); ps += __shfl_xor(ps, mk, 64); }
    if (l == 0){ gd[n] = pd + baP[0]; gs[n] = ps; }
}

// ---------------- node GEMM: [y1|y2|wx] = x @ [W1a|W1b|gatw] + head dots ----------------
__global__ __launch_bounds__(256, 2) void k_nodemm(
    const us16* __restrict__ xb, const us16* __restrict__ w1t,
    const us16* __restrict__ gwt, const float* __restrict__ b1,
    const float* __restrict__ aws, const float* __restrict__ awd,
    us16* __restrict__ y1b, us16* __restrict__ y2b, us16* __restrict__ wxb,
    float* __restrict__ asrc, float* __restrict__ adst)
{
    __shared__ __align__(16) us16 sbuf[32*128];   // 8 KB
    int t = threadIdx.x;
    int wv = t >> 6, lane = t & 63, g = lane >> 4, lr = lane & 15;

    short8 fr[3][2][4];
#pragma unroll
    for (int m = 0; m < 3; ++m)
#pragma unroll
        for (int p = 0; p < 2; ++p){
            int crow = (wv + 4*p)*16 + lr;
#pragma unroll
            for (int kk = 0; kk < 4; ++kk){
                fr[m][p][kk] = (m < 2)
                    ? *(const short8*)(w1t + crow*256 + m*128 + kk*32 + g*8)
                    : *(const short8*)(gwt + crow*128 + kk*32 + g*8);
            }
        }
    float aw_s0 = aws[2*lane], aw_s1 = aws[2*lane+1];
    float aw_d0 = awd[2*lane], aw_d1 = awd[2*lane+1];
    float b1v[2][4];
#pragma unroll
    for (int p = 0; p < 2; ++p) ld4f(b1 + (wv + 4*p)*16 + g*4, b1v[p]);

    for (int tile = blockIdx.x; tile < NNT32; tile += gridDim.x){
        int n0 = tile * 32;
        f32x4 acc[3][2][2];
#pragma unroll
        for (int m = 0; m < 3; ++m)
#pragma unroll
            for (int p = 0; p < 2; ++p)
#pragma unroll
                for (int et = 0; et < 2; ++et) acc[m][p][et] = (f32x4)(0.f);

#pragma unroll
        for (int et = 0; et < 2; ++et){
            int nrow = n0 + et*16 + lr; if (nrow >= NN) nrow = NN - 1;
            short8 bF[4];
#pragma unroll
            for (int kk = 0; kk < 4; ++kk)
                bF[kk] = *(const short8*)(xb + (size_t)nrow*HIDN + kk*32 + g*8);
#pragma unroll
            for (int m = 0; m < 3; ++m)
#pragma unroll
                for (int p = 0; p < 2; ++p)
#pragma unroll
                    for (int kk = 0; kk < 4; ++kk)
                        acc[m][p][et] = __builtin_amdgcn_mfma_f32_16x16x32_bf16(fr[m][p][kk], bF[kk], acc[m][p][et], 0, 0, 0);
        }

#pragma unroll
        for (int m = 0; m < 3; ++m){
#pragma unroll
            for (int p = 0; p < 2; ++p)
#pragma unroll
                for (int et = 0; et < 2; ++et){
                    int row = et*16 + lr;
                    int swz = (row & 7) << 3;
                    int c0 = (wv + 4*p)*16 + g*4;
#pragma unroll
                    for (int r = 0; r < 4; ++r){
                        float v = acc[m][p][et][r] + ((m == 0) ? b1v[p][r] : 0.f);
                        sbuf[row*128 + ((c0 + r) ^ swz)] = f2b(v);
                    }
                }
            __syncthreads();
            us16* dst = (m == 0) ? y1b : (m == 1) ? y2b : wxb;
            {
                int row = t >> 3, q = t & 7;
                int n = n0 + row;
                if (n < NN){
                    int swz = (row & 7) << 3;
#pragma unroll
                    for (int j = 0; j < 2; ++j){
                        int col = q*16 + j*8;
                        *(short8*)(dst + (size_t)n*HIDN + col) = *(const short8*)(sbuf + row*128 + (col ^ swz));
                    }
                }
            }
            if (m == 2){
#pragma unroll
                for (int i = 0; i < 8; ++i){
                    int rw = wv*8 + i;
                    int n2 = n0 + rw;
                    int ci = (2*lane) ^ ((rw & 7) << 3);
                    u32 v = *(const u32*)(sbuf + rw*128 + ci);
                    float x0 = b2f((us16)(v & 0xFFFFu)), x1 = b2f((us16)(v >> 16));
                    float ps = x0*aw_s0 + x1*aw_s1;
                    float pd = x0*aw_d0 + x1*aw_d1;
#pragma unroll
                    for (int mk = 8; mk >= 1; mk >>= 1){ ps += __shfl_xor(ps, mk, 64); pd += __shfl_xor(pd, mk, 64); }
                    if ((lane & 15) == 0 && n2 < NN){
                        int h = lane >> 4;
                        asrc[(size_t)n2*4 + h] = ps;
                        adst[(size_t)n2*4 + h] = pd;
                    }
                }
            }
            __syncthreads();
        }
    }
}

// ---------------- edge kernel: in-register A-frags, 64 edges/block, wave-local out ----------------
__global__ __launch_bounds__(256, 4) void k_edgeconv2(
    const us16* __restrict__ y1b, const us16* __restrict__ y2b,
    const int* __restrict__ csr_src, const int* __restrict__ csr_dst,
    const us16* __restrict__ w2s, const float* __restrict__ lngE,
    const float* __restrict__ lnbE, const float* __restrict__ b2,
    const float* __restrict__ gd, const float* __restrict__ gs,
    us16* __restrict__ msg)
{
    __shared__ __align__(16) u32 bsl[2][2048];   // 16 KB dbuf W2 slices
    __shared__ __align__(16) us16 outS[4*16*128]; // 16 KB, 4 KB per wave
    int t = threadIdx.x;
    int wv = t >> 6, lane = t & 63, g = lane >> 4, lr = lane & 15;
    int bid = (int)blockIdx.x;
    int sb = (bid & 7) * EB64_PER_XCD + (bid >> 3);
    int e0 = sb * 64;

    const u32* w2u = (const u32*)w2s;
    u32 rS[8];
#pragma unroll
    for (int q = 0; q < 8; ++q) rS[q] = w2u[t + 256*q];   // slice 0 issued early

    // ---- phase A (register-resident): gather 32 channels of edge lr ----
    int e = e0 + wv*16 + lr;
    int ec = (e < NE) ? e : NE - 1;
    int d = csr_dst[ec], s = csr_src[ec];
    float gate = 1.f / (1.f + __expf(-(gd[d] + gs[s])));

    float vv[32];
    {
        short8 ra[4], rb[4];
#pragma unroll
        for (int kk = 0; kk < 4; ++kk){
            ra[kk] = *(const short8*)(y1b + (size_t)d*HIDN + kk*32 + g*8);
            rb[kk] = *(const short8*)(y2b + (size_t)s*HIDN + kk*32 + g*8);
        }
        float s1 = 0.f, s2 = 0.f;
#pragma unroll
        for (int kk = 0; kk < 4; ++kk)
#pragma unroll
            for (int j = 0; j < 8; ++j){
                float v = lrelu(b2f((us16)ra[kk][j]) + b2f((us16)rb[kk][j]));
                vv[kk*8+j] = v; s1 += v; s2 += v*v;
            }
        s1 += __shfl_xor(s1, 16, 64); s2 += __shfl_xor(s2, 16, 64);
        s1 += __shfl_xor(s1, 32, 64); s2 += __shfl_xor(s2, 32, 64);
        float mean = s1 * (1.f/128.f);
        float var  = s2 * (1.f/128.f) - mean*mean;
        float inv  = rsqrtf(var + 1e-5f);
#pragma unroll
        for (int kk = 0; kk < 4; ++kk){
            float lg[4], lg2[4], lb[4], lb2[4];
            int c0 = kk*32 + g*8;
            ld4f(lngE + c0, lg);  ld4f(lngE + c0 + 4, lg2);
            ld4f(lnbE + c0, lb);  ld4f(lnbE + c0 + 4, lb2);
#pragma unroll
            for (int j = 0; j < 4; ++j){
                vv[kk*8+j]   = (vv[kk*8+j]   - mean)*inv*lg[j]  + lb[j];
                vv[kk*8+4+j] = (vv[kk*8+4+j] - mean)*inv*lg2[j] + lb2[j];
            }
        }
    }
    short8 aF[4];
#pragma unroll
    for (int kk = 0; kk < 4; ++kk)
#pragma unroll
        for (int j = 0; j < 8; ++j)
            aF[kk][j] = (short)f2b(vv[kk*8+j]);

    // stage W2 slice 0, prefetch slice 1
#pragma unroll
    for (int q = 0; q < 8; ++q) bsl[0][swzi(t + 256*q)] = rS[q];
#pragma unroll
    for (int q = 0; q < 8; ++q) rS[q] = w2u[2048 + t + 256*q];
    __syncthreads();

    // ---- GEMM2: [16 edges x 128] @ [128 x 128] per wave, 4 K-phases ----
    f32x4 acc[8];
#pragma unroll
    for (int nt = 0; nt < 8; ++nt) acc[nt] = (f32x4)(0.f);
#pragma unroll
    for (int kk = 0; kk < 4; ++kk){
        const us16* bp = (const us16*)bsl[kk & 1];
#pragma unroll
        for (int nt = 0; nt < 8; ++nt){
            int row = nt*16 + lr;
            short8 bF = *(const short8*)(bp + row*32 + (g*8 ^ (((row>>1)&3)<<3)));
            acc[nt] = __builtin_amdgcn_mfma_f32_16x16x32_bf16(aF[kk], bF, acc[nt], 0, 0, 0);
        }
        if (kk < 3){
#pragma unroll
            for (int q = 0; q < 8; ++q) bsl[(kk+1)&1][swzi(t + 256*q)] = rS[q];
            if (kk < 2){
#pragma unroll
                for (int q = 0; q < 8; ++q) rS[q] = w2u[(kk+2)*2048 + t + 256*q];
            }
            __syncthreads();
        }
    }

    // ---- epilogue: bias + lrelu + gate -> wave-local outS ----
    float b2v[8];
#pragma unroll
    for (int nt = 0; nt < 8; ++nt) b2v[nt] = b2[nt*16 + lr];
    us16* os = outS + wv*2048;
#pragma unroll
    for (int r = 0; r < 4; ++r){
        int i = g*4 + r;
        float gi = __shfl(gate, i, 64);
        int swz = (i & 7) << 3;
#pragma unroll
        for (int nt = 0; nt < 8; ++nt){
            float v = lrelu(acc[nt][r] + b2v[nt]) * gi;
            os[i*128 + ((nt*16 + lr) ^ swz)] = f2b(v);
        }
    }
    {
        int row = lane >> 2, q = lane & 3;
        int ew = e0 + wv*16 + row;
        if (ew < NE){
            int swz = (row & 7) << 3;
#pragma unroll
            for (int j = 0; j < 4; ++j){
                int col = q*32 + j*8;
                *(short8*)(msg + (size_t)ew*HIDN + col) = *(const short8*)(os + row*128 + (col ^ swz));
            }
        }
    }
}

// ---------------- fused node update (pipelined src prefetch) ----------------
__global__ __launch_bounds__(256, 8) void k_node_update(
    const int* __restrict__ rowptr, const int* __restrict__ csr_src,
    const us16* __restrict__ msg, const us16* __restrict__ wxb,
    const float* __restrict__ asrc, const float* __restrict__ adst,
    const float* __restrict__ xc, const float* __restrict__ gbias,
    const float* __restrict__ lng, const float* __restrict__ lnb,
    float* __restrict__ xout, us16* __restrict__ xbout, int maxmode)
{
    int wv = threadIdx.x >> 6, l = threadIdx.x & 63;
    int n = blockIdx.x*4 + wv;
    if (n >= NN) return;
    int c0 = 2*l, c1 = 2*l + 1;
    int h = l >> 4;

    int b = rowptr[n], en = rowptr[n+1];
    int deg = en - b;

    float adst_h = adst[(size_t)n*4 + h];
    float pself = __expf(fminf(lrelu(asrc[(size_t)n*4 + h] + adst_h), 80.f));
    u32 wq = *(const u32*)(wxb + (size_t)n*HIDN + c0);
    float att0 = pself * b2f((us16)(wq & 0xFFFFu));
    float att1 = pself * b2f((us16)(wq >> 16));
    float den = pself;

    float agg0, agg1;
    if (maxmode){ agg0 = agg1 = -3.0e38f; } else { agg0 = agg1 = 0.f; }

    int s_cur = (deg > 0) ? csr_src[b] : 0;
    for (int i = b; i < en; ++i){
        int s = s_cur;
        if (i + 1 < en) s_cur = csr_src[i + 1];
        u32 mq = *(const u32*)(msg + (size_t)i*HIDN + c0);
        float asr = asrc[(size_t)s*4 + h];
        u32 wq2 = *(const u32*)(wxb + (size_t)s*HIDN + c0);
        float m0 = b2f((us16)(mq & 0xFFFFu)), m1 = b2f((us16)(mq >> 16));
        if (maxmode){ agg0 = fmaxf(agg0, m0); agg1 = fmaxf(agg1, m1); }
        else        { agg0 += m0; agg1 += m1; }
        float p = __expf(fminf(lrelu(asr + adst_h), 80.f));
        att0 = fmaf(p, b2f((us16)(wq2 & 0xFFFFu)), att0);
        att1 = fmaf(p, b2f((us16)(wq2 >> 16)), att1);
        den += p;
    }
    float rden = 1.f / den;
    att0 *= rden; att1 *= rden;
    if (maxmode){ if (deg == 0){ agg0 = 0.f; agg1 = 0.f; } }
    else { float rd = 1.f / fmaxf((float)deg, 1.f); agg0 *= rd; agg1 *= rd; }

    float2 xcv = *(const float2*)(xc + (size_t)n*HIDN + c0);
    float s0 = xcv.x + agg0 + att0 + gbias[c0];
    float s1 = xcv.y + agg1 + att1 + gbias[c1];

    float ss = s0 + s1, ss2 = s0*s0 + s1*s1;
#pragma unroll
    for (int mk = 32; mk >= 1; mk >>= 1){ ss += __shfl_xor(ss, mk, 64); ss2 += __shfl_xor(ss2, mk, 64); }
    float mean = ss * (1.f/128.f);
    float var  = ss2 * (1.f/128.f) - mean*mean;
    float inv  = rsqrtf(var + 1e-5f);
    float o0 = lrelu((s0-mean)*inv*lng[c0] + lnb[c0]);
    float o1 = lrelu((s1-mean)*inv*lng[c1] + lnb[c1]);
    *(float2*)(xout + (size_t)n*HIDN + c0) = make_float2(o0, o1);
    u32 pk = (u32)f2b(o0) | ((u32)f2b(o1) << 16);
    *(u32*)(xbout + (size_t)n*HIDN + c0) = pk;
}

// ---------------- dueling heads ----------------
__global__ void k_heads(const float* __restrict__ xc,
                        const float* __restrict__ aw1, const float* __restrict__ ab1,
                        const float* __restrict__ ag,  const float* __restrict__ abeta,
                        const float* __restrict__ aw2, const float* __restrict__ ab2,
                        const float* __restrict__ vw1, const float* __restrict__ vb1,
                        const float* __restrict__ vg,  const float* __restrict__ vbeta,
                        const float* __restrict__ vw2, const float* __restrict__ vb2,
                        void* __restrict__ dout, const int* __restrict__ flag){
    __shared__ float red[4];
    __shared__ float ts[128], u1[128], aout[10];
    int t = threadIdx.x;
    ts[t] = xc[t];
    __syncthreads();
    float acc = ab1[t];
    for (int k = 0; k < 128; ++k) acc = fmaf(ts[k], aw1[k*HIDN+t], acc);
    acc = lrelu(acc);
    float mean, inv; ln_stats_128(acc, red, mean, inv);
    u1[t] = (acc-mean)*inv*ag[t] + abeta[t];
    __syncthreads();
    if (t < 10){
        float a = ab2[t];
        for (int k = 0; k < 128; ++k) a = fmaf(u1[k], aw2[k*10+t], a);
        aout[t] = a;
    }
    __syncthreads();
    float accv = vb1[t];
    for (int k = 0; k < 128; ++k) accv = fmaf(ts[k], vw1[k*HIDN+t], accv);
    accv = lrelu(accv);
    float meanv, invv; ln_stats_128(accv, red, meanv, invv);
    float v1 = (accv-meanv)*invv*vg[t] + vbeta[t];
    float pv = v1 * vw2[t];
#pragma unroll
    for (int m = 32; m >= 1; m >>= 1) pv += __shfl_xor(pv, m, 64);
    if ((t & 63) == 0) red[t >> 6] = pv;
    __syncthreads();
    if (t == 0){
        float v = red[0] + red[1] + vb2[0];
        float am = 0.f;
        for (int j = 0; j < 10; ++j) am += aout[j];
        am *= 0.1f;
        int dt = flag[0];
        for (int j = 0; j < 11; ++j){
            float val = (j < 10) ? (v + aout[j] - am) : v;
            if (dt) ((__hip_bfloat16*)dout)[j] = __float2bfloat16(val);
            else    ((float*)dout)[j] = val;
        }
    }
}

extern "C" void kernel_launch(void* const* d_in, const int* in_sizes, int n_in,
                              void* d_out, int out_size, void* d_ws, size_t ws_size,
                              hipStream_t stream)
{
    float* base = (float*)d_ws;
    size_t off = 0;
    auto A = [&](size_t n)->float*{ float* p = base + off; off += (n + 63) & ~(size_t)63; return p; };

    int*   flag   = (int*)A(64);
    float* xf     = A((size_t)NN*4);
    float* new_w  = A(4*HIDN); float* neb = A(HIDN); float* neg_ = A(HIDN); float* nebeta = A(HIDN);
    float* ecb1   = A(NLAY*HIDN);
    float* eclng  = A(NLAY*HIDN); float* eclnb = A(NLAY*HIDN);
    float* ecb2   = A(NLAY*HIDN);
    float* ecwa   = A(NLAY*256);  float* ecba = A(NLAY);
    float* gasrc  = A(NLAY*HIDN); float* gadst = A(NLAY*HIDN); float* gbias = A(NLAY*HIDN);
    float* lng    = A(NLAY*HIDN); float* lnb = A(NLAY*HIDN);
    float* aw1    = A(HIDN*HIDN); float* ab1 = A(HIDN); float* ag = A(HIDN); float* abeta = A(HIDN);
    float* aw2    = A(HIDN*10);   float* ab2 = A(10);
    float* vw1    = A(HIDN*HIDN); float* vb1 = A(HIDN); float* vg = A(HIDN); float* vbeta = A(HIDN);
    float* vw2    = A(HIDN);      float* vb2 = A(1);
    // bf16 weights
    us16* w1t = (us16*)A((size_t)NLAY*W1T/2);
    us16* w2s = (us16*)A((size_t)NLAY*W2S/2);
    us16* gwt = (us16*)A((size_t)NLAY*GWT/2);
    // node buffers
    us16* xb   = (us16*)A((size_t)NN*HIDN/2);
    us16* wxb  = (us16*)A((size_t)NN*HIDN/2);
    us16* y1b  = (us16*)A((size_t)NN*HIDN/2);
    us16* y2b  = (us16*)A((size_t)NN*HIDN/2);
    float* xcA = A((size_t)NN*HIDN);
    float* xcB = A((size_t)NN*HIDN);
    float* gd  = A(NN); float* gs = A(NN);
    // CSR + small
    int* cnt     = (int*)A(NN);
    int* rowptr  = (int*)A(NN+1);
    int* cur     = (int*)A(NN);
    int* csr_src = (int*)A(NE);
    int* csr_dst = (int*)A(NE);
    float* asrc = A(NN*4); float* adst = A(NN*4);
    // messages (CSR-ordered)
    us16* msg = (us16*)A((size_t)NE*HIDN/2);

    const int* ei   = (const int*)d_in[1];
    const int* srcI = ei;
    const int* dstI = ei + NE;

    k_detect<<<1, 1, 0, stream>>>((const u32*)d_in[5], flag);

    ConvTab tab; int cc = 0;
    auto add = [&](int idx, float* dst, int n){ tab.c[cc].s = d_in[idx]; tab.c[cc].d = dst; tab.c[cc].n = n; tab.c[cc].pad = 0; cc++; };
    add(0,  xf,    NN*4);
    add(3,  new_w, 4*HIDN); add(4, neb, HIDN); add(5, neg_, HIDN); add(6, nebeta, HIDN);
    add(12, ecb1, NLAY*HIDN);
    add(13, eclng, NLAY*HIDN);     add(14, eclnb, NLAY*HIDN);
    add(16, ecb2, NLAY*HIDN);
    add(17, ecwa, NLAY*256);       add(18, ecba, NLAY);
    add(20, gasrc, NLAY*HIDN); add(21, gadst, NLAY*HIDN); add(22, gbias, NLAY*HIDN);
    add(23, lng,   NLAY*HIDN); add(24, lnb, NLAY*HIDN);
    add(25, aw1, HIDN*HIDN); add(26, ab1, HIDN); add(27, ag, HIDN); add(28, abeta, HIDN);
    add(29, aw2, HIDN*10);   add(30, ab2, 10);
    add(31, vw1, HIDN*HIDN); add(32, vb1, HIDN); add(33, vg, HIDN); add(34, vbeta, HIDN);
    add(35, vw2, HIDN);      add(36, vb2, 1);
    tab.cnt = cc;
    dim3 cgrid(64, cc);
    k_convert_all<<<cgrid, 256, 0, stream>>>(tab, flag);

    k_prepw<<<(PTOT2+255)/256, 256, 0, stream>>>(d_in[11], d_in[15], d_in[19],
                                                 flag, w1t, w2s, gwt);

    hipMemsetAsync(cnt, 0, NN*sizeof(int), stream);
    k_hist<<<(NE+255)/256, 256, 0, stream>>>(dstI, cnt);
    k_scan<<<1, 256, 0, stream>>>(cnt, rowptr);
    hipMemcpyAsync(cur, rowptr, NN*sizeof(int), hipMemcpyDeviceToDevice, stream);
    k_csrfill<<<(NE+255)/256, 256, 0, stream>>>(srcI, dstI, cur, csr_src, csr_dst);

    k_nodeenc<<<NN, 128, 0, stream>>>(xf, new_w, neb, neg_, nebeta, xcA, xb);

    float* curx = xcA; float* nxt = xcB;
    int nblocks4 = (NN + 3) / 4;
    for (int i = 0; i < NLAY; ++i){
        int maxmode = (i % 2 == 0);

        k_predot<<<nblocks4, 256, 0, stream>>>(curx, ecwa + i*256, ecba + i, gd, gs);

        k_nodemm<<<NNT32, 256, 0, stream>>>(xb, w1t + (size_t)i*W1T,
            gwt + (size_t)i*GWT, ecb1 + i*HIDN,
            gasrc + i*HIDN, gadst + i*HIDN,
            y1b, y2b, wxb, asrc, adst);

        k_edgeconv2<<<EBLOCKS64, 256, 0, stream>>>(y1b, y2b, csr_src, csr_dst,
            w2s + (size_t)i*W2S, eclng + i*HIDN, eclnb + i*HIDN,
            ecb2 + i*HIDN, gd, gs, msg);

        k_node_update<<<nblocks4, 256, 0, stream>>>(rowptr, csr_src, msg, wxb,
            asrc, adst, curx, gbias + i*HIDN, lng + i*HIDN, lnb + i*HIDN,
            nxt, xb, maxmode);

        float* tswap = curx; curx = nxt; nxt = tswap;
    }

    k_heads<<<1, 128, 0, stream>>>(curx, aw1, ab1, ag, abeta, aw2, ab2,
                                   vw1, vb1, vg, vbeta, vw2, vb2, d_out, flag);
}